// Round 1
// baseline (2598.192 us; speedup 1.0000x reference)
//
#include <hip/hip_runtime.h>

// Problem constants
#define TOK 4096      // B*S tokens
#define DD  1024      // model dim
#define NE  8         // experts
#define FF  4096      // ffn dim
#define FC  1024      // F chunk size (FF/FC chunks)
#define NB  8         // batch
#define SS  512       // seq

// GEMM tiling
#define BM 64
#define BN 64
#define BK 16
#define PADL 4        // LDS pad (keeps 16B row alignment)

// Workspace layout (units of 4 bytes)
#define LIN_OFF   0u          // float, 4096*1024       = 4194304
#define MOE_OFF   4194304u    // float, 4096*1024       = 4194304
#define H_OFF     8388608u    // float, 8320*1024       = 8519680 (padded rows)
#define BTOK_OFF  16908288u   // int,   NE*TOK          = 32768
#define CNT_OFF   16941056u   // int,   NE              = 8
#define OFFS_OFF  16941064u   // int,   NE              = 8
#define BW_OFF    16941072u   // float, NE*TOK          = 32768
#define SENT_OFF  16973840u   // float, NB*DD           = 8192
// total ~16982032 words = ~67.9 MB

// ---------------------------------------------------------------------------
// GEMM 1: lin[t][n] = sum_k x[t][k] * W[n][k] + b[n]     (C = X @ W^T + b)
// ---------------------------------------------------------------------------
__global__ __launch_bounds__(256) void k_gemm_lin(
    const float* __restrict__ X, const float* __restrict__ W,
    const float* __restrict__ bias, float* __restrict__ lin) {
  __shared__ float As[BK][BM + PADL];
  __shared__ float Bs[BK][BN + PADL];
  const int m0 = blockIdx.x * BM;
  const int n0 = blockIdx.y * BN;
  const int tid = threadIdx.x;
  const int tx = tid & 15, ty = tid >> 4;
  float acc[4][4] = {};

  for (int k0 = 0; k0 < DD; k0 += BK) {
    const int kk = tid & 15, rb = tid >> 4;
#pragma unroll
    for (int i = 0; i < 4; ++i) {
      int mm = rb + i * 16;
      As[kk][mm] = X[(size_t)(m0 + mm) * DD + k0 + kk];
    }
#pragma unroll
    for (int i = 0; i < 4; ++i) {
      int nn = rb + i * 16;
      Bs[kk][nn] = W[(size_t)(n0 + nn) * DD + k0 + kk];
    }
    __syncthreads();
#pragma unroll
    for (int k = 0; k < BK; ++k) {
      float4 av = *(const float4*)&As[k][ty * 4];
      float4 bv = *(const float4*)&Bs[k][tx * 4];
      float a[4] = {av.x, av.y, av.z, av.w};
      float b4[4] = {bv.x, bv.y, bv.z, bv.w};
#pragma unroll
      for (int i = 0; i < 4; ++i)
#pragma unroll
        for (int j = 0; j < 4; ++j) acc[i][j] += a[i] * b4[j];
    }
    __syncthreads();
  }
  // epilogue: add bias, float4 stores
#pragma unroll
  for (int i = 0; i < 4; ++i) {
    int row = m0 + ty * 4 + i;
    int col = n0 + tx * 4;
    float4 v;
    v.x = acc[i][0] + bias[col + 0];
    v.y = acc[i][1] + bias[col + 1];
    v.z = acc[i][2] + bias[col + 2];
    v.w = acc[i][3] + bias[col + 3];
    *(float4*)&lin[(size_t)row * DD + col] = v;
  }
}

// ---------------------------------------------------------------------------
// Gate: logits = lin @ Wg; softmax top-2 renormalized; bucket routing
// one wave per token
// ---------------------------------------------------------------------------
__global__ __launch_bounds__(64) void k_gate(
    const float* __restrict__ lin, const float* __restrict__ Wg,
    int* __restrict__ cnt, int* __restrict__ btok, float* __restrict__ bwp) {
  const int t = blockIdx.x;
  const int lane = threadIdx.x;
  float acc[NE] = {};
  const float* lr = lin + (size_t)t * DD;
  for (int d = lane; d < DD; d += 64) {
    float v = lr[d];
    const float* wgr = Wg + (size_t)d * NE;
    float4 g0 = *(const float4*)(wgr);
    float4 g1 = *(const float4*)(wgr + 4);
    acc[0] += v * g0.x; acc[1] += v * g0.y; acc[2] += v * g0.z; acc[3] += v * g0.w;
    acc[4] += v * g1.x; acc[5] += v * g1.y; acc[6] += v * g1.z; acc[7] += v * g1.w;
  }
#pragma unroll
  for (int off = 32; off > 0; off >>= 1) {
#pragma unroll
    for (int e = 0; e < NE; ++e) acc[e] += __shfl_xor(acc[e], off);
  }
  if (lane == 0) {
    // top-2 of logits (softmax is monotonic); stable ties -> lowest index
    int i1 = 0;
#pragma unroll
    for (int e = 1; e < NE; ++e)
      if (acc[e] > acc[i1]) i1 = e;
    int i2 = (i1 == 0) ? 1 : 0;
#pragma unroll
    for (int e = 0; e < NE; ++e)
      if (e != i1 && acc[e] > acc[i2]) i2 = e;
    // renormalized top-2 softmax weights
    float r = __expf(acc[i2] - acc[i1]);
    float wA = 1.0f / (1.0f + r);
    float wB = r / (1.0f + r);
    int s1 = atomicAdd(&cnt[i1], 1);
    btok[i1 * TOK + s1] = t; bwp[i1 * TOK + s1] = wA;
    int s2 = atomicAdd(&cnt[i2], 1);
    btok[i2 * TOK + s2] = t; bwp[i2 * TOK + s2] = wB;
  }
}

__global__ void k_scan(const int* __restrict__ cnt, int* __restrict__ offs) {
  if (threadIdx.x == 0) {
    int s = 0;
    for (int e = 0; e < NE; ++e) { offs[e] = s; s += cnt[e]; }
  }
}

// ---------------------------------------------------------------------------
// GEMM 2 (per F-chunk): h[gp][f] = relu( lin[tok(p)][:] @ w1[e][:, f0+f] + b1 )
// ---------------------------------------------------------------------------
__global__ __launch_bounds__(256) void k_gemm_h(
    const float* __restrict__ lin, const float* __restrict__ w1,
    const float* __restrict__ b1, const int* __restrict__ cnt,
    const int* __restrict__ offs, const int* __restrict__ btok,
    float* __restrict__ h, int f0) {
  const int e = blockIdx.z;
  const int c = cnt[e];
  const int pt = blockIdx.y;
  if (pt * BM >= c) return;
  const int n0 = blockIdx.x * BN;  // col within chunk

  __shared__ float As[BK][BM + PADL];
  __shared__ float Bs[BK][BN + PADL];
  __shared__ int ts[BM];

  const int tid = threadIdx.x;
  if (tid < BM) {
    int p = pt * BM + tid;
    ts[tid] = (p < c) ? btok[e * TOK + p] : 0;
  }
  __syncthreads();

  const float* w1e = w1 + (size_t)e * DD * FF;
  const int tx = tid & 15, ty = tid >> 4;
  float acc[4][4] = {};

  for (int k0 = 0; k0 < DD; k0 += BK) {
    {
      const int kk = tid & 15, rb = tid >> 4;
#pragma unroll
      for (int i = 0; i < 4; ++i) {
        int mm = rb + i * 16;
        As[kk][mm] = lin[(size_t)ts[mm] * DD + k0 + kk];
      }
    }
    {
      const int nn = tid & 63, kb = tid >> 6;
#pragma unroll
      for (int i = 0; i < 4; ++i) {
        int kk = kb + i * 4;
        Bs[kk][nn] = w1e[(size_t)(k0 + kk) * FF + f0 + n0 + nn];
      }
    }
    __syncthreads();
#pragma unroll
    for (int k = 0; k < BK; ++k) {
      float4 av = *(const float4*)&As[k][ty * 4];
      float4 bv = *(const float4*)&Bs[k][tx * 4];
      float a[4] = {av.x, av.y, av.z, av.w};
      float b4[4] = {bv.x, bv.y, bv.z, bv.w};
#pragma unroll
      for (int i = 0; i < 4; ++i)
#pragma unroll
        for (int j = 0; j < 4; ++j) acc[i][j] += a[i] * b4[j];
    }
    __syncthreads();
  }

  const int gbase = offs[e] + pt * BM;
#pragma unroll
  for (int i = 0; i < 4; ++i) {
    int p = pt * BM + ty * 4 + i;
    if (p < c) {
      int gp = offs[e] + pt * BM + ty * 4 + i;
      int col = n0 + tx * 4;
      float4 v;
      v.x = fmaxf(acc[i][0] + b1[e * FF + f0 + col + 0], 0.f);
      v.y = fmaxf(acc[i][1] + b1[e * FF + f0 + col + 1], 0.f);
      v.z = fmaxf(acc[i][2] + b1[e * FF + f0 + col + 2], 0.f);
      v.w = fmaxf(acc[i][3] + b1[e * FF + f0 + col + 3], 0.f);
      *(float4*)&h[(size_t)gp * FC + col] = v;
    }
  }
  (void)gbase;
}

// ---------------------------------------------------------------------------
// GEMM 3 (per F-chunk): moe[t][d] += w_p * ( h[gp][:] @ w2[e][f0:f0+FC][d] (+b2) )
// ---------------------------------------------------------------------------
__global__ __launch_bounds__(256) void k_gemm_out(
    const float* __restrict__ h, const float* __restrict__ w2,
    const float* __restrict__ b2, const int* __restrict__ cnt,
    const int* __restrict__ offs, const int* __restrict__ btok,
    const float* __restrict__ bwp, float* __restrict__ moe, int f0, int addb2) {
  const int e = blockIdx.z;
  const int c = cnt[e];
  const int pt = blockIdx.y;
  if (pt * BM >= c) return;
  const int n0 = blockIdx.x * BN;  // d col

  __shared__ float As[BK][BM + PADL];
  __shared__ float Bs[BK][BN + PADL];

  const int tid = threadIdx.x;
  const int off = offs[e];
  const float* w2e = w2 + (size_t)e * FF * DD;
  const int tx = tid & 15, ty = tid >> 4;
  float acc[4][4] = {};

  for (int k0 = 0; k0 < FC; k0 += BK) {
    {
      const int kk = tid & 15, rb = tid >> 4;
#pragma unroll
      for (int i = 0; i < 4; ++i) {
        int mm = rb + i * 16;
        // rows past count read padded garbage; masked at epilogue
        As[kk][mm] = h[(size_t)(off + pt * BM + mm) * FC + k0 + kk];
      }
    }
    {
      const int nn = tid & 63, kb = tid >> 6;
#pragma unroll
      for (int i = 0; i < 4; ++i) {
        int kk = kb + i * 4;
        Bs[kk][nn] = w2e[(size_t)(f0 + k0 + kk) * DD + n0 + nn];
      }
    }
    __syncthreads();
#pragma unroll
    for (int k = 0; k < BK; ++k) {
      float4 av = *(const float4*)&As[k][ty * 4];
      float4 bv = *(const float4*)&Bs[k][tx * 4];
      float a[4] = {av.x, av.y, av.z, av.w};
      float b4[4] = {bv.x, bv.y, bv.z, bv.w};
#pragma unroll
      for (int i = 0; i < 4; ++i)
#pragma unroll
        for (int j = 0; j < 4; ++j) acc[i][j] += a[i] * b4[j];
    }
    __syncthreads();
  }

#pragma unroll
  for (int i = 0; i < 4; ++i) {
    int p = pt * BM + ty * 4 + i;
    if (p < c) {
      int t = btok[e * TOK + p];
      float w = bwp[e * TOK + p];
#pragma unroll
      for (int j = 0; j < 4; ++j) {
        int col = n0 + tx * 4 + j;
        float v = acc[i][j];
        if (addb2) v += b2[e * DD + col];
        atomicAdd(&moe[(size_t)t * DD + col], w * v);
      }
    }
  }
}

// ---------------------------------------------------------------------------
// Mean pool over sequence: sent[b][d] = mean_s (x + moe)
// ---------------------------------------------------------------------------
__global__ __launch_bounds__(256) void k_pool(
    const float* __restrict__ x, const float* __restrict__ moe,
    float* __restrict__ sent) {
  const int b = blockIdx.y;
  const int d = blockIdx.x * 256 + threadIdx.x;
  const float* xb = x + (size_t)b * SS * DD + d;
  const float* mb = moe + (size_t)b * SS * DD + d;
  float a = 0.f;
  for (int s = 0; s < SS; ++s) a += xb[(size_t)s * DD] + mb[(size_t)s * DD];
  sent[b * DD + d] = a * (1.0f / SS);
}

// ---------------------------------------------------------------------------
// Loss: -mean_b log_softmax(sent)[b, y[b]]
// ---------------------------------------------------------------------------
__global__ __launch_bounds__(1024) void k_loss(
    const float* __restrict__ sent, const int* __restrict__ y,
    float* __restrict__ out) {
  __shared__ float red[16];
  const int tid = threadIdx.x;
  const int lane = tid & 63, wv = tid >> 6;
  float loss = 0.f;
  for (int b = 0; b < NB; ++b) {
    float v = sent[b * DD + tid];
    float m = v;
#pragma unroll
    for (int off = 32; off > 0; off >>= 1) m = fmaxf(m, __shfl_xor(m, off));
    if (lane == 0) red[wv] = m;
    __syncthreads();
    float m2 = red[0];
#pragma unroll
    for (int w = 1; w < 16; ++w) m2 = fmaxf(m2, red[w]);
    __syncthreads();
    float ex = __expf(v - m2);
#pragma unroll
    for (int off = 32; off > 0; off >>= 1) ex += __shfl_xor(ex, off);
    if (lane == 0) red[wv] = ex;
    __syncthreads();
    if (tid == 0) {
      float se = 0.f;
      for (int w = 0; w < 16; ++w) se += red[w];
      float lse = m2 + logf(se);
      loss += lse - sent[b * DD + y[b]];
    }
    __syncthreads();
  }
  if (tid == 0) out[0] = loss / NB;
}

// ---------------------------------------------------------------------------
extern "C" void kernel_launch(void* const* d_in, const int* in_sizes, int n_in,
                              void* d_out, int out_size, void* d_ws,
                              size_t ws_size, hipStream_t stream) {
  const float* x  = (const float*)d_in[0];
  const int*   y  = (const int*)d_in[1];
  const float* W  = (const float*)d_in[2];
  const float* bb = (const float*)d_in[3];
  const float* Wg = (const float*)d_in[4];
  const float* w1 = (const float*)d_in[5];
  const float* b1 = (const float*)d_in[6];
  const float* w2 = (const float*)d_in[7];
  const float* b2 = (const float*)d_in[8];
  float* out = (float*)d_out;

  float* ws   = (float*)d_ws;
  float* lin  = ws + LIN_OFF;
  float* moe  = ws + MOE_OFF;
  float* h    = ws + H_OFF;
  int*   btok = (int*)(ws + BTOK_OFF);
  int*   cnt  = (int*)(ws + CNT_OFF);
  int*   offs = (int*)(ws + OFFS_OFF);
  float* bwp  = ws + BW_OFF;
  float* sent = ws + SENT_OFF;

  // zero routing counters + moe accumulator (ws is poisoned each call)
  hipMemsetAsync(cnt, 0, NE * sizeof(int), stream);
  hipMemsetAsync(moe, 0, (size_t)TOK * DD * sizeof(float), stream);

  // 1) lin = x @ W^T + b
  k_gemm_lin<<<dim3(TOK / BM, DD / BN), 256, 0, stream>>>(x, W, bb, lin);

  // 2) gate + routing
  k_gate<<<TOK, 64, 0, stream>>>(lin, Wg, cnt, btok, bwp);
  k_scan<<<1, 64, 0, stream>>>(cnt, offs);

  // 3) expert FFN, F chunked
  for (int cidx = 0; cidx < FF / FC; ++cidx) {
    int f0 = cidx * FC;
    k_gemm_h<<<dim3(FC / BN, TOK / BM, NE), 256, 0, stream>>>(
        lin, w1, b1, cnt, offs, btok, h, f0);
    k_gemm_out<<<dim3(DD / BN, TOK / BM, NE), 256, 0, stream>>>(
        h, w2, b2, cnt, offs, btok, bwp, moe, f0, cidx == 0 ? 1 : 0);
  }

  // 4) pool + loss
  k_pool<<<dim3(DD / 256, NB), 256, 0, stream>>>(x, moe, sent);
  k_loss<<<1, 1024, 0, stream>>>(sent, y, out);
}

// Round 2
// 1016.120 us; speedup vs baseline: 2.5570x; 2.5570x over previous
//
#include <hip/hip_runtime.h>

// Problem constants
#define TOK 4096      // B*S tokens
#define DD  1024      // model dim
#define NE  8         // experts
#define FF  4096      // ffn dim
#define FC  1024      // F chunk
#define NB  8         // batch
#define SS  512       // seq
#define HROWS 8320    // 8192 token-pairs + per-expert tile padding (<=127*8)

typedef unsigned short ushort_t;
typedef __attribute__((ext_vector_type(8))) short bshort8;   // 8 bf16 = 4 VGPRs
typedef __attribute__((ext_vector_type(4))) float floatx4;   // MFMA C/D

// fp32 -> bf16 round-to-nearest-even
__device__ __forceinline__ ushort_t f2bf(float f) {
  unsigned int u = __float_as_uint(f);
  u += 0x7fffu + ((u >> 16) & 1u);
  return (ushort_t)(u >> 16);
}
__device__ __forceinline__ float bf2f(ushort_t h) {
  return __uint_as_float(((unsigned int)h) << 16);
}

// async 16B global->LDS (dest is wave-uniform base + lane*16)
__device__ __forceinline__ void gl_lds16(const ushort_t* g, ushort_t* l) {
  __builtin_amdgcn_global_load_lds(
      (const __attribute__((address_space(1))) unsigned int*)g,
      (__attribute__((address_space(3))) unsigned int*)l, 16, 0, 0);
}

// ---------------------------------------------------------------------------
// fp32 -> bf16 cast (vectorized), n4 = element count / 4
// ---------------------------------------------------------------------------
__global__ __launch_bounds__(256) void k_cast(
    const float* __restrict__ in, ushort_t* __restrict__ out, int n4) {
  int i = blockIdx.x * 256 + threadIdx.x;
  if (i < n4) {
    float4 v = ((const float4*)in)[i];
    ushort4 o;
    o.x = f2bf(v.x); o.y = f2bf(v.y); o.z = f2bf(v.z); o.w = f2bf(v.w);
    ((ushort4*)out)[i] = o;
  }
}

// ---------------------------------------------------------------------------
// Transpose + cast: out[c][r] = bf16(in[r][c]), 1024x1024 per z (expert)
// ---------------------------------------------------------------------------
__global__ __launch_bounds__(256) void k_transpose_cast(
    const float* __restrict__ in, size_t in_estride, int in_rstride,
    ushort_t* __restrict__ out, size_t out_estride) {
  __shared__ ushort_t t[64][70];
  const float* ib = in + blockIdx.z * in_estride;
  ushort_t* ob = out + blockIdx.z * out_estride;
  const int r0 = blockIdx.y * 64, c0 = blockIdx.x * 64;
  const int tid = threadIdx.x;
  const int lr = tid >> 4, lc4 = (tid & 15) * 4;
#pragma unroll
  for (int it = 0; it < 4; ++it) {
    int r = lr + it * 16;
    float4 v = *(const float4*)&ib[(size_t)(r0 + r) * in_rstride + c0 + lc4];
    t[r][lc4 + 0] = f2bf(v.x);
    t[r][lc4 + 1] = f2bf(v.y);
    t[r][lc4 + 2] = f2bf(v.z);
    t[r][lc4 + 3] = f2bf(v.w);
  }
  __syncthreads();
  const int oc = tid >> 5, od2 = (tid & 31) * 2;
#pragma unroll
  for (int it = 0; it < 8; ++it) {
    int cc = oc + it * 8;
    ushort2 w;
    w.x = t[od2 + 0][cc];
    w.y = t[od2 + 1][cc];
    *(ushort2*)&ob[(size_t)(c0 + cc) * 1024 + r0 + od2] = w;
  }
}

// ---------------------------------------------------------------------------
// MFMA GEMM, 128x128 tile, BK=32, K=1024, N=1024, bf16 inputs, fp32 acc.
// MODE 0: lin = x_bf @ W_bf^T + b          -> bf16 Obf (rows = m0+m)
// MODE 1: h   = relu(lin[gather] @ w1t^T + b1) -> bf16 Obf (rows = off+m0+m)
// MODE 2: out_buf(+)= h @ w2t^T (+b2 when accum==0) -> fp32 Of, masked p<c
// B matrix is n-major [1024][1024] bf16 (k contiguous).
// ---------------------------------------------------------------------------
template <int MODE>
__global__ __launch_bounds__(256) void k_mfma(
    const ushort_t* __restrict__ A, const ushort_t* __restrict__ Bm,
    const float* __restrict__ bias, ushort_t* __restrict__ Obf,
    float* __restrict__ Of, const int* __restrict__ cnt,
    const int* __restrict__ offs, const int* __restrict__ btok, int f0,
    int accum) {
  const int e = (MODE == 0) ? 0 : blockIdx.z;
  int c = TOK, off = 0;
  if (MODE != 0) {
    c = cnt[e];
    off = offs[e];
    if ((int)blockIdx.y * 128 >= c) return;
  }
  const int m0 = blockIdx.y * 128;
  const int n0 = blockIdx.x * 128;
  const ushort_t* Bp = (MODE == 0) ? Bm : Bm + (size_t)e * 1024 * 1024;

  __shared__ ushort_t Als[128 * 32];
  __shared__ ushort_t Bls[128 * 32];
  __shared__ int ts[128];

  const int tid = threadIdx.x;
  if (tid < 128) {
    int p = m0 + tid;
    int r;
    if (MODE == 0) r = p;
    else if (MODE == 1) r = btok[e * TOK + min(p, c - 1)];
    else r = off + p;
    ts[tid] = r;
  }

  const int lane = tid & 63;
  const int w = tid >> 6;
  const int wm = (w & 1) * 64, wn = (w >> 1) * 64;
  const int lm = lane & 15, lq = lane >> 4;
  const int sr = lane >> 2;   // row within 16-row staging group
  const int sg = lane & 3;    // 16B group within row

  floatx4 zero = {0.f, 0.f, 0.f, 0.f};
  floatx4 acc[4][4];
#pragma unroll
  for (int i = 0; i < 4; ++i)
#pragma unroll
    for (int j = 0; j < 4; ++j) acc[i][j] = zero;

  for (int k0 = 0; k0 < 1024; k0 += 32) {
    __syncthreads();  // previous iter's frag reads done; ts[] visible (iter 0)
    // stage A: wave w covers local rows w*32 .. w*32+31 (2 insts of 16 rows)
#pragma unroll
    for (int i = 0; i < 2; ++i) {
      int r = w * 32 + i * 16 + sr;
      int q = (sg - (r >> 1)) & 3;  // source 16B group (swizzle on global side)
      const ushort_t* src = A + (size_t)ts[r] * 1024 + k0 + q * 8;
      ushort_t* dst = Als + r * 32 + sg * 8;  // = uniform base + lane*8
      gl_lds16(src, dst);
    }
    // stage B
#pragma unroll
    for (int i = 0; i < 2; ++i) {
      int r = w * 32 + i * 16 + sr;
      int q = (sg - (r >> 1)) & 3;
      const ushort_t* src = Bp + (size_t)(n0 + r) * 1024 + k0 + q * 8;
      ushort_t* dst = Bls + r * 32 + sg * 8;
      gl_lds16(src, dst);
    }
    __syncthreads();  // drain global_load_lds before frag reads

    bshort8 af[4], bfr[4];
#pragma unroll
    for (int i = 0; i < 4; ++i) {
      int r = wm + i * 16 + lm;
      af[i] = *(const bshort8*)&Als[r * 32 + (((lq + (r >> 1)) & 3) * 8)];
    }
#pragma unroll
    for (int j = 0; j < 4; ++j) {
      int r = wn + j * 16 + lm;
      bfr[j] = *(const bshort8*)&Bls[r * 32 + (((lq + (r >> 1)) & 3) * 8)];
    }
#pragma unroll
    for (int i = 0; i < 4; ++i)
#pragma unroll
      for (int j = 0; j < 4; ++j)
        acc[i][j] = __builtin_amdgcn_mfma_f32_16x16x32_bf16(af[i], bfr[j],
                                                            acc[i][j], 0, 0, 0);
  }

  // epilogue: C mapping col = lane&15, row = (lane>>4)*4 + reg  [m89-verified]
#pragma unroll
  for (int i = 0; i < 4; ++i) {
#pragma unroll
    for (int j = 0; j < 4; ++j) {
      int n = wn + j * 16 + lm;  // local col 0..127
#pragma unroll
      for (int rr = 0; rr < 4; ++rr) {
        int m = wm + i * 16 + lq * 4 + rr;  // local row 0..127
        float v = acc[i][j][rr];
        if (MODE == 0) {
          int gn = n0 + n;
          v += bias[gn];
          Obf[(size_t)(m0 + m) * 1024 + gn] = f2bf(v);
        } else if (MODE == 1) {
          int gn = n0 + n;
          v += bias[(size_t)e * FF + f0 + gn];
          v = fmaxf(v, 0.f);
          Obf[(size_t)(off + m0 + m) * 1024 + gn] = f2bf(v);
        } else {
          int p = m0 + m;
          if (p < c) {
            int gn = n0 + n;
            if (!accum) v += bias[(size_t)e * DD + gn];
            float* dp = &Of[(size_t)(off + p) * 1024 + gn];
            if (accum) *dp += v; else *dp = v;
          }
        }
      }
    }
  }
}

// ---------------------------------------------------------------------------
// Gate: logits = lin_bf @ Wg; top-2 renormalized softmax; bucket + slot record
// ---------------------------------------------------------------------------
__global__ __launch_bounds__(64) void k_gate(
    const ushort_t* __restrict__ lin_bf, const float* __restrict__ Wg,
    int* __restrict__ cnt, int* __restrict__ btok, int* __restrict__ eslot,
    float* __restrict__ wts) {
  const int t = blockIdx.x;
  const int lane = threadIdx.x;
  float acc[NE] = {};
  const ushort_t* lr = lin_bf + (size_t)t * DD + lane * 16;
#pragma unroll
  for (int u = 0; u < 16; ++u) {
    float v = bf2f(lr[u]);
    const float* wgr = Wg + (size_t)(lane * 16 + u) * NE;
    float4 g0 = *(const float4*)(wgr);
    float4 g1 = *(const float4*)(wgr + 4);
    acc[0] += v * g0.x; acc[1] += v * g0.y; acc[2] += v * g0.z; acc[3] += v * g0.w;
    acc[4] += v * g1.x; acc[5] += v * g1.y; acc[6] += v * g1.z; acc[7] += v * g1.w;
  }
#pragma unroll
  for (int off = 32; off > 0; off >>= 1) {
#pragma unroll
    for (int e = 0; e < NE; ++e) acc[e] += __shfl_xor(acc[e], off);
  }
  if (lane == 0) {
    int i1 = 0;
#pragma unroll
    for (int e = 1; e < NE; ++e)
      if (acc[e] > acc[i1]) i1 = e;
    int i2 = (i1 == 0) ? 1 : 0;
#pragma unroll
    for (int e = 0; e < NE; ++e)
      if (e != i1 && acc[e] > acc[i2]) i2 = e;
    float r = __expf(acc[i2] - acc[i1]);
    float wA = 1.0f / (1.0f + r);
    float wB = r / (1.0f + r);
    int s1 = atomicAdd(&cnt[i1], 1);
    btok[i1 * TOK + s1] = t;
    int s2 = atomicAdd(&cnt[i2], 1);
    btok[i2 * TOK + s2] = t;
    eslot[2 * t + 0] = i1 * TOK + s1; wts[2 * t + 0] = wA;
    eslot[2 * t + 1] = i2 * TOK + s2; wts[2 * t + 1] = wB;
  }
}

__global__ void k_scan(const int* __restrict__ cnt, int* __restrict__ offs) {
  if (threadIdx.x == 0) {
    int s = 0;
    for (int e = 0; e < NE; ++e) { offs[e] = s; s += cnt[e]; }
  }
}

// ---------------------------------------------------------------------------
// Pool: sent[b][d] = (1/S) * sum_s ( x + w0*ob[gp0] + w1*ob[gp1] )
// grid (DD/256, NB, 8): z splits the s-loop, partials via atomicAdd
// ---------------------------------------------------------------------------
__global__ __launch_bounds__(256) void k_pool(
    const float* __restrict__ x, const float* __restrict__ ob,
    const int* __restrict__ offs, const int* __restrict__ eslot,
    const float* __restrict__ wts, float* __restrict__ sent) {
  const int b = blockIdx.y;
  const int d = blockIdx.x * 256 + threadIdx.x;
  const int sc = blockIdx.z;
  float a = 0.f;
  for (int s = sc * 64; s < sc * 64 + 64; ++s) {
    int t = b * SS + s;
    int e0 = eslot[2 * t], e1 = eslot[2 * t + 1];
    int g0 = offs[e0 >> 12] + (e0 & (TOK - 1));
    int g1 = offs[e1 >> 12] + (e1 & (TOK - 1));
    a += x[(size_t)t * DD + d] + wts[2 * t] * ob[(size_t)g0 * DD + d] +
         wts[2 * t + 1] * ob[(size_t)g1 * DD + d];
  }
  atomicAdd(&sent[b * DD + d], a * (1.0f / SS));
}

// ---------------------------------------------------------------------------
// Loss: -mean_b log_softmax(sent)[b, y[b]]
// ---------------------------------------------------------------------------
__global__ __launch_bounds__(1024) void k_loss(
    const float* __restrict__ sent, const int* __restrict__ y,
    float* __restrict__ out) {
  __shared__ float red[16];
  const int tid = threadIdx.x;
  const int lane = tid & 63, wv = tid >> 6;
  float loss = 0.f;
  for (int b = 0; b < NB; ++b) {
    float v = sent[b * DD + tid];
    float m = v;
#pragma unroll
    for (int off = 32; off > 0; off >>= 1) m = fmaxf(m, __shfl_xor(m, off));
    if (lane == 0) red[wv] = m;
    __syncthreads();
    float m2 = red[0];
#pragma unroll
    for (int w = 1; w < 16; ++w) m2 = fmaxf(m2, red[w]);
    __syncthreads();
    float ex = __expf(v - m2);
#pragma unroll
    for (int off = 32; off > 0; off >>= 1) ex += __shfl_xor(ex, off);
    if (lane == 0) red[wv] = ex;
    __syncthreads();
    if (tid == 0) {
      float se = 0.f;
      for (int w = 0; w < 16; ++w) se += red[w];
      float lse = m2 + logf(se);
      loss += lse - sent[b * DD + y[b]];
    }
    __syncthreads();
  }
  if (tid == 0) out[0] = loss / NB;
}

// ---------------------------------------------------------------------------
// Workspace byte offsets (all 16B aligned); total ~104 MB
// ---------------------------------------------------------------------------
#define B_LINBF 0ull                  // bf16 [TOK][DD]          8,388,608
#define B_XBF   8388608ull            // bf16 [TOK][DD]          8,388,608
#define B_WBF   16777216ull           // bf16 [DD][DD]           2,097,152
#define B_HBF   18874368ull           // bf16 [HROWS][FC]       17,039,360
#define B_W1T   35913728ull           // bf16 [NE][FC][DD]      16,777,216
#define B_W2T   52690944ull           // bf16 [NE][DD][FC]      16,777,216
#define B_OB    69468160ull           // fp32 [HROWS][DD]       34,078,720
#define B_BTOK  103546880ull          // int  [NE][TOK]            131,072
#define B_CNT   103677952ull          // int  [16]                      64
#define B_OFFS  103678016ull          // int  [16]                      64
#define B_ESL   103678080ull          // int  [2*TOK]               32,768
#define B_WTS   103710848ull          // f32  [2*TOK]               32,768
#define B_SENT  103743616ull          // f32  [NB][DD]              32,768

extern "C" void kernel_launch(void* const* d_in, const int* in_sizes, int n_in,
                              void* d_out, int out_size, void* d_ws,
                              size_t ws_size, hipStream_t stream) {
  const float* x  = (const float*)d_in[0];
  const int*   y  = (const int*)d_in[1];
  const float* W  = (const float*)d_in[2];
  const float* bb = (const float*)d_in[3];
  const float* Wg = (const float*)d_in[4];
  const float* w1 = (const float*)d_in[5];
  const float* b1 = (const float*)d_in[6];
  const float* w2 = (const float*)d_in[7];
  const float* b2 = (const float*)d_in[8];
  float* out = (float*)d_out;

  char* base = (char*)d_ws;
  ushort_t* lin_bf = (ushort_t*)(base + B_LINBF);
  ushort_t* x_bf   = (ushort_t*)(base + B_XBF);
  ushort_t* W_bf   = (ushort_t*)(base + B_WBF);
  ushort_t* h_bf   = (ushort_t*)(base + B_HBF);
  ushort_t* w1t    = (ushort_t*)(base + B_W1T);
  ushort_t* w2t    = (ushort_t*)(base + B_W2T);
  float*    ob     = (float*)(base + B_OB);
  int*      btok   = (int*)(base + B_BTOK);
  int*      cnt    = (int*)(base + B_CNT);
  int*      offs   = (int*)(base + B_OFFS);
  int*      eslot  = (int*)(base + B_ESL);
  float*    wts    = (float*)(base + B_WTS);
  float*    sent   = (float*)(base + B_SENT);

  hipMemsetAsync(cnt, 0, 64, stream);
  hipMemsetAsync(sent, 0, NB * DD * sizeof(float), stream);

  // cast x, W to bf16
  k_cast<<<(TOK * DD / 4 + 255) / 256, 256, 0, stream>>>(x, x_bf, TOK * DD / 4);
  k_cast<<<(DD * DD / 4 + 255) / 256, 256, 0, stream>>>(W, W_bf, DD * DD / 4);

  // lin = x @ W^T + b  (bf16 out)
  k_mfma<0><<<dim3(8, 32), 256, 0, stream>>>(x_bf, W_bf, bb, lin_bf, nullptr,
                                             nullptr, nullptr, nullptr, 0, 0);

  // gate + routing
  k_gate<<<TOK, 64, 0, stream>>>(lin_bf, Wg, cnt, btok, eslot, wts);
  k_scan<<<1, 64, 0, stream>>>(cnt, offs);

  // expert FFN, F chunked
  for (int cidx = 0; cidx < FF / FC; ++cidx) {
    int f0 = cidx * FC;
    // w1[:, :, f0:f0+FC] -> w1t [e][f][d]
    k_transpose_cast<<<dim3(16, 16, NE), 256, 0, stream>>>(
        w1 + f0, (size_t)DD * FF, FF, w1t, (size_t)FC * DD);
    k_mfma<1><<<dim3(8, 32, NE), 256, 0, stream>>>(
        lin_bf, w1t, b1, h_bf, nullptr, cnt, offs, btok, f0, 0);
    // w2[:, f0:f0+FC, :] -> w2t [e][d][f]
    k_transpose_cast<<<dim3(16, 16, NE), 256, 0, stream>>>(
        w2 + (size_t)f0 * DD, (size_t)FF * DD, DD, w2t, (size_t)DD * FC);
    k_mfma<2><<<dim3(8, 32, NE), 256, 0, stream>>>(
        h_bf, w2t, b2, nullptr, ob, cnt, offs, btok, f0, cidx > 0 ? 1 : 0);
  }

  // pool + loss
  k_pool<<<dim3(DD / 256, NB, 8), 256, 0, stream>>>(x, ob, offs, eslot, wts,
                                                    sent);
  k_loss<<<1, 1024, 0, stream>>>(sent, y, out);
}

// Round 3
// 688.332 us; speedup vs baseline: 3.7746x; 1.4762x over previous
//
#include <hip/hip_runtime.h>

// Problem constants
#define TOK 4096      // B*S tokens
#define DD  1024      // model dim
#define NE  8         // experts
#define FF  4096      // ffn dim
#define NB  8         // batch
#define SS  512       // seq
#define HROWS 8320    // 8192 token-pairs + per-expert tile padding

typedef unsigned short ushort_t;
typedef __attribute__((ext_vector_type(8))) short bshort8;   // 8 bf16 = 4 VGPRs
typedef __attribute__((ext_vector_type(4))) float floatx4;   // MFMA C/D

__device__ __forceinline__ ushort_t f2bf(float f) {
  unsigned int u = __float_as_uint(f);
  u += 0x7fffu + ((u >> 16) & 1u);
  return (ushort_t)(u >> 16);
}
__device__ __forceinline__ float bf2f(ushort_t h) {
  return __uint_as_float(((unsigned int)h) << 16);
}

// async 16B global->LDS (LDS dest = wave-uniform base + lane*16)
__device__ __forceinline__ void gl_lds16(const ushort_t* g, ushort_t* l) {
  __builtin_amdgcn_global_load_lds(
      (const __attribute__((address_space(1))) unsigned int*)g,
      (__attribute__((address_space(3))) unsigned int*)l, 16, 0, 0);
}

// ---------------------------------------------------------------------------
// fp32 -> bf16 cast
// ---------------------------------------------------------------------------
__global__ __launch_bounds__(256) void k_cast(
    const float* __restrict__ in, ushort_t* __restrict__ out, int n4) {
  int i = blockIdx.x * 256 + threadIdx.x;
  if (i < n4) {
    float4 v = ((const float4*)in)[i];
    ushort4 o;
    o.x = f2bf(v.x); o.y = f2bf(v.y); o.z = f2bf(v.z); o.w = f2bf(v.w);
    ((ushort4*)out)[i] = o;
  }
}

// ---------------------------------------------------------------------------
// Transpose + cast: out[c][r] = bf16(in[r][c]); 64x64 tiles; strides as args
// grid: (cols/64, rows/64, NE)
// ---------------------------------------------------------------------------
__global__ __launch_bounds__(256) void k_transpose_cast(
    const float* __restrict__ in, size_t in_estride, int in_rstride,
    ushort_t* __restrict__ out, size_t out_estride, int out_rstride) {
  __shared__ ushort_t t[64][70];
  const float* ib = in + blockIdx.z * in_estride;
  ushort_t* ob = out + blockIdx.z * out_estride;
  const int r0 = blockIdx.y * 64, c0 = blockIdx.x * 64;
  const int tid = threadIdx.x;
  const int lr = tid >> 4, lc4 = (tid & 15) * 4;
#pragma unroll
  for (int it = 0; it < 4; ++it) {
    int r = lr + it * 16;
    float4 v = *(const float4*)&ib[(size_t)(r0 + r) * in_rstride + c0 + lc4];
    t[r][lc4 + 0] = f2bf(v.x);
    t[r][lc4 + 1] = f2bf(v.y);
    t[r][lc4 + 2] = f2bf(v.z);
    t[r][lc4 + 3] = f2bf(v.w);
  }
  __syncthreads();
  const int oc = tid >> 5, od2 = (tid & 31) * 2;
#pragma unroll
  for (int it = 0; it < 8; ++it) {
    int cc = oc + it * 8;
    ushort2 w;
    w.x = t[od2 + 0][cc];
    w.y = t[od2 + 1][cc];
    *(ushort2*)&ob[(size_t)(c0 + cc) * out_rstride + r0 + od2] = w;
  }
}

// ---------------------------------------------------------------------------
// MFMA GEMM, 128x128 tile, BK=32, bf16 in, fp32 acc. Runtime strides:
//   kext: K extent (= B row stride), ast: A row stride, ost: MODE1 out stride
// MODE 0: lin = A @ B^T + bias              -> bf16 Obf rows m0+m, stride DD
// MODE 1: h   = relu(A[gather] @ B^T + b1)  -> bf16 Obf rows off+p, stride ost
// MODE 2: ob (+)= A @ B^T (+b2 if !accum)   -> fp32 Of rows off+p, stride DD
// ---------------------------------------------------------------------------
template <int MODE>
__global__ __launch_bounds__(256) void k_mfma(
    const ushort_t* __restrict__ A, const ushort_t* __restrict__ Bm,
    const float* __restrict__ bias, ushort_t* __restrict__ Obf,
    float* __restrict__ Of, const int* __restrict__ cnt,
    const int* __restrict__ offs, const int* __restrict__ btok, int f0,
    int accum, int kext, int ast, int ost, size_t bstride) {
  const int e = (MODE == 0) ? 0 : blockIdx.z;
  int c = TOK, off = 0;
  if (MODE != 0) {
    c = cnt[e];
    off = offs[e];
    if ((int)blockIdx.y * 128 >= c) return;
  }
  const int m0 = blockIdx.y * 128;
  const int n0 = blockIdx.x * 128;
  const ushort_t* Bp = (MODE == 0) ? Bm : Bm + (size_t)e * bstride;

  __shared__ ushort_t Als[128 * 32];
  __shared__ ushort_t Bls[128 * 32];
  __shared__ int ts[128];

  const int tid = threadIdx.x;
  if (tid < 128) {
    int p = m0 + tid;
    int r;
    if (MODE == 0) r = p;
    else if (MODE == 1) r = btok[e * TOK + min(p, c - 1)];
    else r = off + p;
    ts[tid] = r;
  }

  const int lane = tid & 63;
  const int w = tid >> 6;
  const int wm = (w & 1) * 64, wn = (w >> 1) * 64;
  const int lm = lane & 15, lq = lane >> 4;
  const int sr = lane >> 2;   // row within 16-row staging group
  const int sg = lane & 3;    // 16B group within row

  floatx4 zero = {0.f, 0.f, 0.f, 0.f};
  floatx4 acc[4][4];
#pragma unroll
  for (int i = 0; i < 4; ++i)
#pragma unroll
    for (int j = 0; j < 4; ++j) acc[i][j] = zero;

  for (int k0 = 0; k0 < kext; k0 += 32) {
    __syncthreads();  // prev frag reads done; ts[] visible (iter 0)
#pragma unroll
    for (int i = 0; i < 2; ++i) {
      int r = w * 32 + i * 16 + sr;
      int q = (sg - (r >> 1)) & 3;  // XOR-swizzle on the global side
      const ushort_t* src = A + (size_t)ts[r] * ast + k0 + q * 8;
      ushort_t* dst = Als + r * 32 + sg * 8;
      gl_lds16(src, dst);
    }
#pragma unroll
    for (int i = 0; i < 2; ++i) {
      int r = w * 32 + i * 16 + sr;
      int q = (sg - (r >> 1)) & 3;
      const ushort_t* src = Bp + (size_t)(n0 + r) * kext + k0 + q * 8;
      ushort_t* dst = Bls + r * 32 + sg * 8;
      gl_lds16(src, dst);
    }
    __syncthreads();  // drain global_load_lds

    bshort8 af[4], bfr[4];
#pragma unroll
    for (int i = 0; i < 4; ++i) {
      int r = wm + i * 16 + lm;
      af[i] = *(const bshort8*)&Als[r * 32 + (((lq + (r >> 1)) & 3) * 8)];
    }
#pragma unroll
    for (int j = 0; j < 4; ++j) {
      int r = wn + j * 16 + lm;
      bfr[j] = *(const bshort8*)&Bls[r * 32 + (((lq + (r >> 1)) & 3) * 8)];
    }
#pragma unroll
    for (int i = 0; i < 4; ++i)
#pragma unroll
      for (int j = 0; j < 4; ++j)
        acc[i][j] = __builtin_amdgcn_mfma_f32_16x16x32_bf16(af[i], bfr[j],
                                                            acc[i][j], 0, 0, 0);
  }

  // epilogue: C mapping col = lane&15, row = (lane>>4)*4 + reg  [m89-verified]
#pragma unroll
  for (int i = 0; i < 4; ++i) {
#pragma unroll
    for (int j = 0; j < 4; ++j) {
      int n = wn + j * 16 + lm;
#pragma unroll
      for (int rr = 0; rr < 4; ++rr) {
        int m = wm + i * 16 + lq * 4 + rr;
        float v = acc[i][j][rr];
        if (MODE == 0) {
          int gn = n0 + n;
          v += bias[gn];
          Obf[(size_t)(m0 + m) * DD + gn] = f2bf(v);
        } else if (MODE == 1) {
          int p = m0 + m;
          if (p < c) {  // mask: rows past count belong to the next expert
            int gn = n0 + n;
            v += bias[(size_t)e * FF + f0 + gn];
            v = fmaxf(v, 0.f);
            Obf[(size_t)(off + p) * ost + gn] = f2bf(v);
          }
        } else {
          int p = m0 + m;
          if (p < c) {
            int gn = n0 + n;
            if (!accum) v += bias[(size_t)e * DD + gn];
            float* dp = &Of[(size_t)(off + p) * DD + gn];
            if (accum) *dp += v; else *dp = v;
          }
        }
      }
    }
  }
}

// ---------------------------------------------------------------------------
// Phase 1 gate: logits + top-2 + renormalized weights. No atomics.
// 4 tokens per block (1 wave each).
// ---------------------------------------------------------------------------
__global__ __launch_bounds__(256) void k_logits(
    const ushort_t* __restrict__ lin_bf, const float* __restrict__ Wg,
    int* __restrict__ topi, float* __restrict__ wts) {
  const int wv = threadIdx.x >> 6, lane = threadIdx.x & 63;
  const int t = blockIdx.x * 4 + wv;
  float acc[NE] = {};
  const ushort_t* lr = lin_bf + (size_t)t * DD;
#pragma unroll 4
  for (int d0 = 0; d0 < DD; d0 += 64) {
    float v = bf2f(lr[d0 + lane]);
    const float* wgr = Wg + (size_t)(d0 + lane) * NE;
    float4 g0 = *(const float4*)(wgr);
    float4 g1 = *(const float4*)(wgr + 4);
    acc[0] += v * g0.x; acc[1] += v * g0.y; acc[2] += v * g0.z; acc[3] += v * g0.w;
    acc[4] += v * g1.x; acc[5] += v * g1.y; acc[6] += v * g1.z; acc[7] += v * g1.w;
  }
#pragma unroll
  for (int off = 32; off > 0; off >>= 1) {
#pragma unroll
    for (int e = 0; e < NE; ++e) acc[e] += __shfl_xor(acc[e], off);
  }
  if (lane == 0) {
    int i1 = 0;
#pragma unroll
    for (int e = 1; e < NE; ++e)
      if (acc[e] > acc[i1]) i1 = e;
    int i2 = (i1 == 0) ? 1 : 0;
#pragma unroll
    for (int e = 0; e < NE; ++e)
      if (e != i1 && acc[e] > acc[i2]) i2 = e;
    float r = __expf(acc[i2] - acc[i1]);
    topi[t] = i1 | (i2 << 4);
    wts[2 * t + 0] = 1.0f / (1.0f + r);
    wts[2 * t + 1] = r / (1.0f + r);
  }
}

// ---------------------------------------------------------------------------
// Phase 2 route: single block, deterministic counting-sort of 8192 assignments
// ---------------------------------------------------------------------------
#define RT 512
__global__ __launch_bounds__(RT) void k_route(
    const int* __restrict__ topi, int* __restrict__ cnt, int* __restrict__ offs,
    int* __restrict__ btok, int* __restrict__ eslot) {
  __shared__ int sc[NE][RT + 1];
  __shared__ int tot[NE];
  const int tid = threadIdx.x;
  int lc[NE] = {};
  int my[8];
#pragma unroll
  for (int i = 0; i < 8; ++i) {
    int t = tid * 8 + i;
    int p = topi[t];
    my[i] = p;
    lc[p & 15]++;
    lc[(p >> 4) & 15]++;
  }
#pragma unroll
  for (int e = 0; e < NE; ++e) sc[e][tid] = lc[e];
  __syncthreads();
  if (tid < NE) {  // serial exclusive scan per expert (8 lanes in parallel)
    int s = 0;
    for (int i = 0; i < RT; ++i) { int v = sc[tid][i]; sc[tid][i] = s; s += v; }
    tot[tid] = s;
  }
  __syncthreads();
  if (tid == 0) {
    int s = 0;
    for (int e = 0; e < NE; ++e) { offs[e] = s; cnt[e] = tot[e]; s += tot[e]; }
  }
  __syncthreads();
  int run[NE];
#pragma unroll
  for (int e = 0; e < NE; ++e) run[e] = sc[e][tid];
#pragma unroll
  for (int i = 0; i < 8; ++i) {
    int t = tid * 8 + i, p = my[i];
    int e1 = p & 15, e2 = (p >> 4) & 15;
    int s1 = run[e1]++;
    btok[e1 * TOK + s1] = t;
    eslot[2 * t + 0] = e1 * TOK + s1;
    int s2 = run[e2]++;
    btok[e2 * TOK + s2] = t;
    eslot[2 * t + 1] = e2 * TOK + s2;
  }
}

// ---------------------------------------------------------------------------
// Pool: sent[b][d] = (1/S) * sum_s ( x + w0*ob[gp0] + w1*ob[gp1] )
// ---------------------------------------------------------------------------
__global__ __launch_bounds__(256) void k_pool(
    const float* __restrict__ x, const float* __restrict__ ob,
    const int* __restrict__ offs, const int* __restrict__ eslot,
    const float* __restrict__ wts, float* __restrict__ sent) {
  const int b = blockIdx.y;
  const int d = blockIdx.x * 256 + threadIdx.x;
  const int sc = blockIdx.z;
  float a = 0.f;
  for (int s = sc * 64; s < sc * 64 + 64; ++s) {
    int t = b * SS + s;
    int e0 = eslot[2 * t], e1 = eslot[2 * t + 1];
    int g0 = offs[e0 >> 12] + (e0 & (TOK - 1));
    int g1 = offs[e1 >> 12] + (e1 & (TOK - 1));
    a += x[(size_t)t * DD + d] + wts[2 * t] * ob[(size_t)g0 * DD + d] +
         wts[2 * t + 1] * ob[(size_t)g1 * DD + d];
  }
  atomicAdd(&sent[b * DD + d], a * (1.0f / SS));
}

// ---------------------------------------------------------------------------
// Loss
// ---------------------------------------------------------------------------
__global__ __launch_bounds__(1024) void k_loss(
    const float* __restrict__ sent, const int* __restrict__ y,
    float* __restrict__ out) {
  __shared__ float red[16];
  const int tid = threadIdx.x;
  const int lane = tid & 63, wv = tid >> 6;
  float loss = 0.f;
  for (int b = 0; b < NB; ++b) {
    float v = sent[b * DD + tid];
    float m = v;
#pragma unroll
    for (int off = 32; off > 0; off >>= 1) m = fmaxf(m, __shfl_xor(m, off));
    if (lane == 0) red[wv] = m;
    __syncthreads();
    float m2 = red[0];
#pragma unroll
    for (int w = 1; w < 16; ++w) m2 = fmaxf(m2, red[w]);
    __syncthreads();
    float ex = __expf(v - m2);
#pragma unroll
    for (int off = 32; off > 0; off >>= 1) ex += __shfl_xor(ex, off);
    if (lane == 0) red[wv] = ex;
    __syncthreads();
    if (tid == 0) {
      float se = 0.f;
      for (int w = 0; w < 16; ++w) se += red[w];
      loss += m2 + logf(se) - sent[b * DD + y[b]];
    }
    __syncthreads();
  }
  if (tid == 0) out[0] = loss / NB;
}

// ---------------------------------------------------------------------------
extern "C" void kernel_launch(void* const* d_in, const int* in_sizes, int n_in,
                              void* d_out, int out_size, void* d_ws,
                              size_t ws_size, hipStream_t stream) {
  const float* x  = (const float*)d_in[0];
  const int*   y  = (const int*)d_in[1];
  const float* W  = (const float*)d_in[2];
  const float* bb = (const float*)d_in[3];
  const float* Wg = (const float*)d_in[4];
  const float* w1 = (const float*)d_in[5];
  const float* b1 = (const float*)d_in[6];
  const float* w2 = (const float*)d_in[7];
  const float* b2 = (const float*)d_in[8];
  float* out = (float*)d_out;

  // workspace layout for a given chunk width FCr (ws_size is launch-invariant,
  // so this branch is identical every call — graph-capture safe)
  auto need = [](size_t FCr) -> size_t {
    size_t o = 0;
    auto al = [&](size_t b) { o = (o + b + 255) & ~255ull; };
    al((size_t)TOK * DD * 2);           // lin_bf
    al((size_t)TOK * DD * 2);           // x_bf
    al((size_t)DD * DD * 2);            // W_bf
    al((size_t)HROWS * FCr * 2);        // h_bf
    al((size_t)NE * FCr * DD * 2);      // w1t
    al((size_t)NE * DD * FCr * 2);      // w2t
    al((size_t)HROWS * DD * 4);         // ob
    al((size_t)NE * TOK * 4);           // btok
    al(64); al(64);                     // cnt, offs
    al((size_t)TOK * 4);                // topi
    al((size_t)2 * TOK * 4);            // eslot
    al((size_t)2 * TOK * 4);            // wts
    al((size_t)NB * DD * 4);            // sent
    return o;
  };
  const int nchunks = (ws_size >= need(FF)) ? 1 : 4;
  const int FCr = FF / nchunks;

  char* base = (char*)d_ws;
  size_t o = 0;
  auto al = [&](size_t b) -> char* {
    char* p = base + o;
    o = (o + b + 255) & ~255ull;
    return p;
  };
  ushort_t* lin_bf = (ushort_t*)al((size_t)TOK * DD * 2);
  ushort_t* x_bf   = (ushort_t*)al((size_t)TOK * DD * 2);
  ushort_t* W_bf   = (ushort_t*)al((size_t)DD * DD * 2);
  ushort_t* h_bf   = (ushort_t*)al((size_t)HROWS * FCr * 2);
  ushort_t* w1t    = (ushort_t*)al((size_t)NE * FCr * DD * 2);
  ushort_t* w2t    = (ushort_t*)al((size_t)NE * DD * FCr * 2);
  float*    ob     = (float*)al((size_t)HROWS * DD * 4);
  int*      btok   = (int*)al((size_t)NE * TOK * 4);
  int*      cnt    = (int*)al(64);
  int*      offs   = (int*)al(64);
  int*      topi   = (int*)al((size_t)TOK * 4);
  int*      eslot  = (int*)al((size_t)2 * TOK * 4);
  float*    wts    = (float*)al((size_t)2 * TOK * 4);
  float*    sent   = (float*)al((size_t)NB * DD * 4);

  hipMemsetAsync(sent, 0, NB * DD * sizeof(float), stream);

  // cast x, W to bf16
  k_cast<<<TOK * DD / 4 / 256, 256, 0, stream>>>(x, x_bf, TOK * DD / 4);
  k_cast<<<DD * DD / 4 / 256, 256, 0, stream>>>(W, W_bf, DD * DD / 4);

  // lin = x @ W^T + b
  k_mfma<0><<<dim3(DD / 128, TOK / 128), 256, 0, stream>>>(
      x_bf, W_bf, bb, lin_bf, nullptr, nullptr, nullptr, nullptr, 0, 0,
      DD, DD, DD, 0);

  // gate (no atomics) + deterministic routing
  k_logits<<<TOK / 4, 256, 0, stream>>>(lin_bf, Wg, topi, wts);
  k_route<<<1, RT, 0, stream>>>(topi, cnt, offs, btok, eslot);

  // expert FFN
  for (int ci = 0; ci < nchunks; ++ci) {
    int f0 = ci * FCr;
    // w1[:, :, f0:f0+FCr] -> w1t [e][f][d]
    k_transpose_cast<<<dim3(FCr / 64, DD / 64, NE), 256, 0, stream>>>(
        w1 + f0, (size_t)DD * FF, FF, w1t, (size_t)FCr * DD, DD);
    k_mfma<1><<<dim3(FCr / 128, TOK / 128, NE), 256, 0, stream>>>(
        lin_bf, w1t, b1, h_bf, nullptr, cnt, offs, btok, f0, 0,
        DD, DD, FCr, (size_t)FCr * DD);
    // w2[:, f0:f0+FCr, :] -> w2t [e][d][f]
    k_transpose_cast<<<dim3(DD / 64, FCr / 64, NE), 256, 0, stream>>>(
        w2 + (size_t)f0 * DD, (size_t)FF * DD, DD, w2t, (size_t)DD * FCr, FCr);
    k_mfma<2><<<dim3(DD / 128, TOK / 128, NE), 256, 0, stream>>>(
        h_bf, w2t, b2, nullptr, ob, cnt, offs, btok, f0, ci > 0 ? 1 : 0,
        FCr, FCr, DD, (size_t)DD * FCr);
  }

  // pool + loss
  k_pool<<<dim3(DD / 256, NB, 8), 256, 0, stream>>>(x, ob, offs, eslot, wts,
                                                    sent);
  k_loss<<<1, 1024, 0, stream>>>(sent, y, out);
}